// Round 5
// baseline (424.696 us; speedup 1.0000x reference)
//
#include <hip/hip_runtime.h>
#include <hip/hip_bf16.h>
#include <math.h>

#define BB 2
#define TT 1024
#define SS 1024
#define DD 1024
#define HH 16
#define DH 64

typedef __attribute__((ext_vector_type(8))) short bf16x8;
typedef __attribute__((ext_vector_type(4))) float f32x4;
typedef unsigned short ushort_t;

#define AS3(p) ((__attribute__((address_space(3))) unsigned int*)(p))
#define AS1(p) ((const __attribute__((address_space(1))) unsigned int*)(p))

__device__ __forceinline__ unsigned short f2b(float f) {
    union { float f; unsigned u; } x; x.f = f;
    unsigned r = x.u + 0x7FFFu + ((x.u >> 16) & 1u);
    return (unsigned short)(r >> 16);
}

__device__ __forceinline__ float b2f(unsigned short u) {
    union { unsigned u; float f; } x; x.u = ((unsigned)u) << 16;
    return x.f;
}

// ---------------------------------------------------------------------------
// fp32 -> bf16 conversion: ONE kernel for all 7 tensors.
// y<3: q/k/v (2M elems, 1024 blocks). y>=3: Wq/Wk/Wv/Wo (1M elems, 512 blocks).
// ---------------------------------------------------------------------------
__global__ __launch_bounds__(256) void cvt_all(
    const float* __restrict__ q, const float* __restrict__ k, const float* __restrict__ v,
    const float* __restrict__ Wq, const float* __restrict__ Wk,
    const float* __restrict__ Wv, const float* __restrict__ Wo,
    ushort_t* __restrict__ oq, ushort_t* __restrict__ ok, ushort_t* __restrict__ ov,
    ushort_t* __restrict__ oWq, ushort_t* __restrict__ oWk,
    ushort_t* __restrict__ oWv, ushort_t* __restrict__ oWo)
{
    const int y = blockIdx.y;
    if (y >= 3 && blockIdx.x >= 512) return;
    const float* src =
        (y == 0) ? q : (y == 1) ? k : (y == 2) ? v :
        (y == 3) ? Wq : (y == 4) ? Wk : (y == 5) ? Wv : Wo;
    ushort_t* dst =
        (y == 0) ? oq : (y == 1) ? ok : (y == 2) ? ov :
        (y == 3) ? oWq : (y == 4) ? oWk : (y == 5) ? oWv : oWo;
    size_t i = ((size_t)blockIdx.x * 256 + threadIdx.x) * 8;
    float4 v0 = *(const float4*)&src[i];
    float4 v1 = *(const float4*)&src[i + 4];
    uint4 o;
    o.x = f2b(v0.x) | ((unsigned)f2b(v0.y) << 16);
    o.y = f2b(v0.z) | ((unsigned)f2b(v0.w) << 16);
    o.z = f2b(v1.x) | ((unsigned)f2b(v1.y) << 16);
    o.w = f2b(v1.z) | ((unsigned)f2b(v1.w) << 16);
    *(uint4*)&dst[i] = o;
}

// ---------------------------------------------------------------------------
// 128x128 bf16 MFMA GEMM mainloop: D = A (MxK) . Bw^T (N x K), both K-contig.
// BK=32, PING-PONG double-buffer: STAGE(k+1,buf^1) -> COMPUTE(buf) -> one
// barrier per step.
// ---------------------------------------------------------------------------
__device__ __forceinline__ void gemm128_mainloop(
    const ushort_t* __restrict__ A,   // pre-offset to (bm,0), row stride K
    const ushort_t* __restrict__ Bw,  // pre-offset to (bn,0), row stride K
    int K, ushort_t (*Asm)[128 * 32], ushort_t (*Bsm)[128 * 32],
    f32x4 acc[4][4])
{
    const int tid = threadIdx.x;
    const int wave = tid >> 6, lane = tid & 63;
    const int sr = lane >> 2;                        // row within 16-row group
    const int gc = (lane & 3) ^ ((lane >> 3) & 3);   // swizzled global chunk
    const int l15 = lane & 15, q = lane >> 4;
    const int mblk = (wave >> 1) * 64, nblk = (wave & 1) * 64;

#define G128_STAGE(k0_, b_) do {                                               \
        _Pragma("unroll")                                                      \
        for (int o = 0; o < 2; o++) {                                          \
            int r0 = (wave * 2 + o) * 16;                                      \
            __builtin_amdgcn_global_load_lds(                                  \
                AS1(A + (size_t)(r0 + sr) * K + (k0_) + gc * 8),               \
                AS3(Asm[b_] + r0 * 32), 16, 0, 0);                             \
            __builtin_amdgcn_global_load_lds(                                  \
                AS1(Bw + (size_t)(r0 + sr) * K + (k0_) + gc * 8),              \
                AS3(Bsm[b_] + r0 * 32), 16, 0, 0);                             \
        } } while (0)

#define G128_COMPUTE(b_) do {                                                  \
        bf16x8 av[4], bv[4];                                                   \
        _Pragma("unroll")                                                      \
        for (int mi = 0; mi < 4; mi++) {                                       \
            int r = mblk + mi * 16 + l15;                                      \
            av[mi] = *(const bf16x8*)&Asm[b_][r * 32 + (q ^ ((r >> 1) & 3)) * 8]; \
        }                                                                      \
        _Pragma("unroll")                                                      \
        for (int ni = 0; ni < 4; ni++) {                                       \
            int r = nblk + ni * 16 + l15;                                      \
            bv[ni] = *(const bf16x8*)&Bsm[b_][r * 32 + (q ^ ((r >> 1) & 3)) * 8]; \
        }                                                                      \
        _Pragma("unroll")                                                      \
        for (int mi = 0; mi < 4; mi++)                                         \
            _Pragma("unroll")                                                  \
            for (int ni = 0; ni < 4; ni++)                                     \
                acc[mi][ni] = __builtin_amdgcn_mfma_f32_16x16x32_bf16(         \
                    av[mi], bv[ni], acc[mi][ni], 0, 0, 0);                     \
        } while (0)

    G128_STAGE(0, 0);
    __syncthreads();                 // drain stage(0)

    int buf = 0;
    for (int k0 = 0; k0 < K; k0 += 32) {
        if (k0 + 32 < K) G128_STAGE(k0 + 32, buf ^ 1);   // prefetch next
        G128_COMPUTE(buf);                                // compute current
        __syncthreads();
        buf ^= 1;
    }
#undef G128_STAGE
#undef G128_COMPUTE
}

// Fused Q/K/V projections: z picks which. Output bf16 (B,T,D).
__global__ __launch_bounds__(256) void proj_gemm(
    const ushort_t* __restrict__ qb, const ushort_t* __restrict__ kb, const ushort_t* __restrict__ vb,
    const ushort_t* __restrict__ Wqb, const ushort_t* __restrict__ Wkb, const ushort_t* __restrict__ Wvb,
    const float* __restrict__ bq, const float* __restrict__ bk, const float* __restrict__ bv,
    ushort_t* __restrict__ qh, ushort_t* __restrict__ kh, ushort_t* __restrict__ vh)
{
    __shared__ ushort_t Asm[2][128 * 32];
    __shared__ ushort_t Bsm[2][128 * 32];
    const int z = blockIdx.z;
    const ushort_t* A = (z == 0) ? qb : (z == 1) ? kb : vb;
    const ushort_t* W = (z == 0) ? Wqb : (z == 1) ? Wkb : Wvb;
    const float* bias = (z == 0) ? bq : (z == 1) ? bk : bv;
    ushort_t* Y = (z == 0) ? qh : (z == 1) ? kh : vh;

    const int bm = blockIdx.y * 128, bn = blockIdx.x * 128;
    f32x4 acc[4][4];
    #pragma unroll
    for (int i = 0; i < 4; i++)
        #pragma unroll
        for (int j = 0; j < 4; j++) acc[i][j] = (f32x4)(0.f);

    gemm128_mainloop(A + (size_t)bm * DD, W + (size_t)bn * DD, DD, Asm, Bsm, acc);

    const int lane = threadIdx.x & 63, wave = threadIdx.x >> 6;
    const int mblk = (wave >> 1) * 64, nblk = (wave & 1) * 64;
    const int l15 = lane & 15, q = lane >> 4;
    #pragma unroll
    for (int mi = 0; mi < 4; mi++) {
        #pragma unroll
        for (int ni = 0; ni < 4; ni++) {
            int col = bn + nblk + ni * 16 + l15;
            float bcol = bias[col];
            #pragma unroll
            for (int r = 0; r < 4; r++) {
                int row = bm + mblk + mi * 16 + q * 4 + r;
                Y[(size_t)row * DD + col] = f2b(acc[mi][ni][r] + bcol);
            }
        }
    }
}

// Output projection: bf16 in, fp32 out + bias.
__global__ __launch_bounds__(256) void oproj_gemm(
    const ushort_t* __restrict__ A, const ushort_t* __restrict__ W,
    const float* __restrict__ bias, float* __restrict__ Y)
{
    __shared__ ushort_t Asm[2][128 * 32];
    __shared__ ushort_t Bsm[2][128 * 32];
    const int bm = blockIdx.y * 128, bn = blockIdx.x * 128;
    f32x4 acc[4][4];
    #pragma unroll
    for (int i = 0; i < 4; i++)
        #pragma unroll
        for (int j = 0; j < 4; j++) acc[i][j] = (f32x4)(0.f);

    gemm128_mainloop(A + (size_t)bm * DD, W + (size_t)bn * DD, DD, Asm, Bsm, acc);

    const int lane = threadIdx.x & 63, wave = threadIdx.x >> 6;
    const int mblk = (wave >> 1) * 64, nblk = (wave & 1) * 64;
    const int l15 = lane & 15, q = lane >> 4;
    #pragma unroll
    for (int mi = 0; mi < 4; mi++) {
        #pragma unroll
        for (int ni = 0; ni < 4; ni++) {
            int col = bn + nblk + ni * 16 + l15;
            float bcol = bias[col];
            #pragma unroll
            for (int r = 0; r < 4; r++) {
                int row = bm + mblk + mi * 16 + q * 4 + r;
                Y[(size_t)row * DD + col] = acc[mi][ni][r] + bcol;
            }
        }
    }
}

// ---------------------------------------------------------------------------
// V transpose: vh (B,S,H,DH) bf16 -> vT (B,H,DH,S) bf16
// ---------------------------------------------------------------------------
__global__ __launch_bounds__(256) void transpose_v(
    const ushort_t* __restrict__ vh, ushort_t* __restrict__ vT)
{
    __shared__ ushort_t Ls[64][72];
    const int s0 = blockIdx.x * 64;
    const int bh = blockIdx.y;
    const int b = bh >> 4, h = bh & 15;
    const int tid = threadIdx.x;
    const int r = tid >> 2, c16 = (tid & 3) * 16;

    const ushort_t* src = &vh[((size_t)(b * SS + s0 + r) * HH + h) * DH + c16];
    uint4 u0 = *(const uint4*)src;
    uint4 u1 = *(const uint4*)(src + 8);
    ushort_t tmp[16];
    *(uint4*)&tmp[0] = u0; *(uint4*)&tmp[8] = u1;
    #pragma unroll
    for (int j = 0; j < 16; j++) Ls[c16 + j][r] = tmp[j];
    __syncthreads();

    const int dh = r;
    uint4 w0 = *(const uint4*)&Ls[dh][c16];
    uint4 w1 = *(const uint4*)&Ls[dh][c16 + 8];
    ushort_t* dst = &vT[((size_t)bh * DH + dh) * SS + s0 + c16];
    *(uint4*)dst = w0;
    *(uint4*)(dst + 8) = w1;
}

// ---------------------------------------------------------------------------
// scores: raw[bh,t,s] = clip(qh.kh/8). 128x128 tile per block, causal tiles
// only. K=64 (one-shot staging, 2 MFMA k-steps). Written fp32 into the attn
// output buffer (overwritten in place by sav_fused).
// ---------------------------------------------------------------------------
__global__ __launch_bounds__(256) void scores_mfma(
    const ushort_t* __restrict__ qh, const ushort_t* __restrict__ kh,
    float* __restrict__ attn)
{
    __shared__ ushort_t Qs[128 * 64];
    __shared__ ushort_t Ks[128 * 64];

    int idx = blockIdx.x, ti = 0;
    while (idx >= ti + 1) { idx -= ti + 1; ti++; }
    const int si = idx;
    const int bh = blockIdx.y;
    const int b = bh >> 4, h = bh & 15;
    const int t0 = ti * 128, s0 = si * 128;

    const int tid = threadIdx.x;
    const int wave = tid >> 6, lane = tid & 63;
    const int sr8 = lane >> 3;                 // 0..7: row within 8-row group
    const int gc8 = (lane & 7) ^ sr8;          // swizzled chunk (8 x 16B per row)

    #pragma unroll
    for (int o = 0; o < 4; o++) {
        int r0 = (wave * 4 + o) * 8;
        int r = r0 + sr8;
        __builtin_amdgcn_global_load_lds(
            AS1(qh + ((size_t)(b * TT + t0 + r) * HH + h) * DH + gc8 * 8),
            AS3(Qs + r0 * 64), 16, 0, 0);
        __builtin_amdgcn_global_load_lds(
            AS1(kh + ((size_t)(b * SS + s0 + r) * HH + h) * DH + gc8 * 8),
            AS3(Ks + r0 * 64), 16, 0, 0);
    }
    __syncthreads();

    const int l15 = lane & 15, q = lane >> 4;
    const int tblk = (wave >> 1) * 64, sblk = (wave & 1) * 64;
    f32x4 acc[4][4];
    #pragma unroll
    for (int i = 0; i < 4; i++)
        #pragma unroll
        for (int j = 0; j < 4; j++) acc[i][j] = (f32x4)(0.f);

    #pragma unroll
    for (int ks = 0; ks < 2; ks++) {
        bf16x8 av[4], bv[4];
        #pragma unroll
        for (int mi = 0; mi < 4; mi++) {
            int r = tblk + mi * 16 + l15;
            av[mi] = *(const bf16x8*)&Qs[r * 64 + ((ks * 4 + q) ^ (r & 7)) * 8];
        }
        #pragma unroll
        for (int ni = 0; ni < 4; ni++) {
            int r = sblk + ni * 16 + l15;
            bv[ni] = *(const bf16x8*)&Ks[r * 64 + ((ks * 4 + q) ^ (r & 7)) * 8];
        }
        #pragma unroll
        for (int mi = 0; mi < 4; mi++)
            #pragma unroll
            for (int ni = 0; ni < 4; ni++)
                acc[mi][ni] = __builtin_amdgcn_mfma_f32_16x16x32_bf16(av[mi], bv[ni], acc[mi][ni], 0, 0, 0);
    }

    #pragma unroll
    for (int mi = 0; mi < 4; mi++) {
        #pragma unroll
        for (int ni = 0; ni < 4; ni++) {
            int scol = s0 + sblk + ni * 16 + l15;
            #pragma unroll
            for (int r = 0; r < 4; r++) {
                int t = t0 + tblk + mi * 16 + q * 4 + r;
                float v = acc[mi][ni][r] * 0.125f;
                v = fminf(fmaxf(v, -80.f), 80.f);
                attn[((size_t)bh * TT + t) * SS + scol] = v;
            }
        }
    }
}

// ---------------------------------------------------------------------------
// FUSED softmax+bias+renorm+AV, single pass over s-tiles.
// Block = 64 t-rows of one (b,h), 512 threads (8 waves), heavy-first.
// Fixed softmax reference max m=16 (scores clipped to +-80, typical ~N(0,1):
// exp(s-16) spans [e^-96, e^64] -- all contributing weights are fp32/bf16
// normal; FTZ-flushed entries have true weight < 1e-6 << tolerance).
// Unnormalized w = exp(s-16)*sc stored bf16 in 128KB LDS; one row-sum reduce
// at the end gives inv for BOTH the fp32 attn write-out and the AV output.
// Zero (masked) tiles stored up front so the stores drain under compute.
// Wave roles: compute-mapping = 8 rows/wave x 8 cols/lane; MFMA-mapping =
// wave (rg = w>>1) rows rg*16..+15, dh half (w&1)*32..+31.
// V staged swizzled via global_load_lds, double-buffered; stage issued AFTER
// the barrier (prev buffer's readers are all pre-barrier -> no race).
// ---------------------------------------------------------------------------
__global__ __launch_bounds__(512) void sav_fused(
    const float* __restrict__ scores,        // raw scores (= attn buffer)
    const float* __restrict__ attn_bias,
    const float* __restrict__ bias_scale_p,
    const ushort_t* __restrict__ vT,
    float* __restrict__ attn,                // final attn (same buffer)
    ushort_t* __restrict__ ao)
{
    __shared__ ushort_t Wlds[64 * 1024];     // 128 KB, XOR-swizzled 16B chunks
    __shared__ ushort_t Vsm[2][64 * 64];     // 16 KB
    __shared__ float sInv[64];

    const int tb = (int)gridDim.x - 1 - (int)blockIdx.x;   // heavy first
    const int bh = blockIdx.y;
    const int b = bh >> 4, h = bh & 15;
    const int t0 = tb * 64;
    const int nst = tb + 1;                  // s-tiles with s <= t

    const int tid = threadIdx.x;
    const int wave = tid >> 6, lane = tid & 63;
    // compute / writeout mapping: row = wave*8 + lane>>3, col chunk = lane&7
    const int crow = wave * 8 + (lane >> 3);
    const int cc8  = (lane & 7) * 8;
    const int csw  = (cc8 ^ ((crow & 7) << 3));      // swizzled chunk (elems)
    const int tglob = t0 + crow;
    // MFMA mapping
    const int rg = wave >> 1, dhh = wave & 1;
    const int l15 = lane & 15, q = lane >> 4;
    const int arow = rg * 16 + l15;
    // V stage mapping
    const int sr8 = lane >> 3, gc8 = (lane & 7) ^ sr8;

    const float bscale = bias_scale_p[0];
    const float* srow = scores    + ((size_t)bh * TT + tglob) * SS + cc8;
    const float* brow = attn_bias + ((size_t)bh * TT + tglob) * SS + cc8;
    const ushort_t* vbase = vT + (size_t)bh * DH * SS;
    float* aout = attn + ((size_t)bh * TT + tglob) * SS + cc8;

    // zero-fill fully-masked tiles first (stores drain under compute)
    {
        float4 z = make_float4(0.f, 0.f, 0.f, 0.f);
        for (int si = nst; si < SS / 64; si++) {
            *(float4*)(aout + si * 64) = z;
            *(float4*)(aout + si * 64 + 4) = z;
        }
    }

    f32x4 acc[2];
    acc[0] = (f32x4)(0.f); acc[1] = (f32x4)(0.f);
    float P = 0.f, Wn = 0.f;

#define STAGE_V(sidx, bb) do {                                                \
        __builtin_amdgcn_global_load_lds(                                     \
            AS1(vbase + (size_t)(wave * 8 + sr8) * SS + (sidx) * 64 + gc8 * 8),\
            AS3(&Vsm[bb][(wave * 8) * 64]), 16, 0, 0); } while (0)

#define LOAD_SB(ti_, sv_, bv_) do {                                           \
        const float* ps_ = srow + (ti_) * 64;                                 \
        const float* pb_ = brow + (ti_) * 64;                                 \
        sv_[0] = *(const float4*)ps_; sv_[1] = *(const float4*)(ps_ + 4);     \
        bv_[0] = *(const float4*)pb_; bv_[1] = *(const float4*)(pb_ + 4); } while (0)

#define COMPUTE_W(ti_, sv_, bv_) do {                                         \
        float sa_[8] = { sv_[0].x, sv_[0].y, sv_[0].z, sv_[0].w,              \
                         sv_[1].x, sv_[1].y, sv_[1].z, sv_[1].w };            \
        float ba_[8] = { bv_[0].x, bv_[0].y, bv_[0].z, bv_[0].w,              \
                         bv_[1].x, bv_[1].y, bv_[1].z, bv_[1].w };            \
        float wv_[8];                                                         \
        _Pragma("unroll")                                                     \
        for (int j = 0; j < 8; j++) {                                         \
            int col_ = (ti_) * 64 + cc8 + j;                                  \
            float p_ = (col_ <= tglob) ? __expf(sa_[j] - 16.f) : 0.f;         \
            float e_ = __expf(-2.f * fabsf(ba_[j]));                          \
            float th_ = copysignf((1.f - e_) / (1.f + e_), ba_[j]);           \
            float sc_ = fmaxf(1.f + bscale * th_, 1e-9f);                     \
            float ww_ = p_ * sc_;                                             \
            P += p_; Wn += ww_; wv_[j] = ww_;                                 \
        }                                                                     \
        union { unsigned u[4]; uint4 v4; } pk_;                               \
        asm("v_cvt_pk_bf16_f32 %0, %1, %2" : "=v"(pk_.u[0]) : "v"(wv_[0]), "v"(wv_[1])); \
        asm("v_cvt_pk_bf16_f32 %0, %1, %2" : "=v"(pk_.u[1]) : "v"(wv_[2]), "v"(wv_[3])); \
        asm("v_cvt_pk_bf16_f32 %0, %1, %2" : "=v"(pk_.u[2]) : "v"(wv_[4]), "v"(wv_[5])); \
        asm("v_cvt_pk_bf16_f32 %0, %1, %2" : "=v"(pk_.u[3]) : "v"(wv_[6]), "v"(wv_[7])); \
        *(uint4*)&Wlds[(size_t)crow * 1024 + (ti_) * 64 + csw] = pk_.v4; } while (0)

#define MFMA_T(ti_, bb) do {                                                  \
        bf16x8 a0 = *(const bf16x8*)&Wlds[(size_t)arow * 1024 + (ti_) * 64 + ((q ^ (arow & 7)) << 3)];       \
        bf16x8 a1 = *(const bf16x8*)&Wlds[(size_t)arow * 1024 + (ti_) * 64 + (((4 + q) ^ (arow & 7)) << 3)]; \
        _Pragma("unroll")                                                     \
        for (int ni = 0; ni < 2; ni++) {                                      \
            int rv = dhh * 32 + ni * 16 + l15;                                \
            bf16x8 b0 = *(const bf16x8*)&Vsm[bb][rv * 64 + ((q ^ (rv & 7)) << 3)];       \
            bf16x8 b1 = *(const bf16x8*)&Vsm[bb][rv * 64 + (((4 + q) ^ (rv & 7)) << 3)]; \
            acc[ni] = __builtin_amdgcn_mfma_f32_16x16x32_bf16(a0, b0, acc[ni], 0, 0, 0); \
            acc[ni] = __builtin_amdgcn_mfma_f32_16x16x32_bf16(a1, b1, acc[ni], 0, 0, 0); \
        } } while (0)

    float4 sA[2], bA[2], sB[2], bB[2];
    STAGE_V(0, 0);
    LOAD_SB(0, sA, bA);

    int st = 0;
    while (true) {
        COMPUTE_W(st, sA, bA);
        __syncthreads();    // w(st) visible + V(st) staged (drained here)
        if (st + 1 < nst) { STAGE_V(st + 1, 1); LOAD_SB(st + 1, sB, bB); }
        MFMA_T(st, 0);
        if (++st == nst) break;

        COMPUTE_W(st, sB, bB);
        __syncthreads();
        if (st + 1 < nst) { STAGE_V(st + 1, 0); LOAD_SB(st + 1, sA, bA); }
        MFMA_T(st, 1);
        if (++st == nst) break;
    }
#undef STAGE_V
#undef LOAD_SB
#undef COMPUTE_W
#undef MFMA_T

    // per-row sums: reduce over the 8 lanes (col chunks) sharing crow
    #pragma unroll
    for (int off = 1; off < 8; off <<= 1) {
        P  += __shfl_xor(P, off);
        Wn += __shfl_xor(Wn, off);
    }
    if ((lane & 7) == 0) sInv[crow] = 1.f / (Wn + 1e-9f * P);
    __syncthreads();

    // write final normalized attn rows from Wlds
    {
        const float rinv = sInv[crow];
        for (int si = 0; si < nst; si++) {
            union { uint4 v4; unsigned u[4]; } pk;
            pk.v4 = *(const uint4*)&Wlds[(size_t)crow * 1024 + si * 64 + csw];
            float4 o0, o1;
            o0.x = b2f((ushort_t)(pk.u[0] & 0xffff)) * rinv;
            o0.y = b2f((ushort_t)(pk.u[0] >> 16)) * rinv;
            o0.z = b2f((ushort_t)(pk.u[1] & 0xffff)) * rinv;
            o0.w = b2f((ushort_t)(pk.u[1] >> 16)) * rinv;
            o1.x = b2f((ushort_t)(pk.u[2] & 0xffff)) * rinv;
            o1.y = b2f((ushort_t)(pk.u[2] >> 16)) * rinv;
            o1.z = b2f((ushort_t)(pk.u[3] & 0xffff)) * rinv;
            o1.w = b2f((ushort_t)(pk.u[3] >> 16)) * rinv;
            *(float4*)(aout + si * 64) = o0;
            *(float4*)(aout + si * 64 + 4) = o1;
        }
    }

    // AV output (bf16), scaled by per-row inv
    #pragma unroll
    for (int ni = 0; ni < 2; ni++) {
        int dh = dhh * 32 + ni * 16 + l15;
        #pragma unroll
        for (int r = 0; r < 4; r++) {
            int trow = rg * 16 + q * 4 + r;
            float iv = sInv[trow];
            int t = t0 + trow;
            ao[(size_t)(b * TT + t) * DD + h * DH + dh] = f2b(acc[ni][r] * iv);
        }
    }
}

// ---------------------------------------------------------------------------
extern "C" void kernel_launch(void* const* d_in, const int* in_sizes, int n_in,
                              void* d_out, int out_size, void* d_ws, size_t ws_size,
                              hipStream_t stream)
{
    const float* q   = (const float*)d_in[0];
    const float* k   = (const float*)d_in[1];
    const float* v   = (const float*)d_in[2];
    const float* attn_bias = (const float*)d_in[4];
    const float* Wq = (const float*)d_in[5];
    const float* bq = (const float*)d_in[6];
    const float* Wk = (const float*)d_in[7];
    const float* bk = (const float*)d_in[8];
    const float* Wv = (const float*)d_in[9];
    const float* bv = (const float*)d_in[10];
    const float* Wo = (const float*)d_in[11];
    const float* bo = (const float*)d_in[12];
    const float* bscale = (const float*)d_in[13];

    // ws layout (32 MB total, with aliasing):
    char* base = (char*)d_ws;
    ushort_t* qb  = (ushort_t*)(base + (0ull << 20));   // 4 MB, later vT
    ushort_t* kb  = (ushort_t*)(base + (4ull << 20));   // 4 MB, later ao
    ushort_t* vb  = (ushort_t*)(base + (8ull << 20));   // 4 MB
    ushort_t* Wqb = (ushort_t*)(base + (12ull << 20));  // 2 MB
    ushort_t* Wkb = (ushort_t*)(base + (14ull << 20));  // 2 MB
    ushort_t* Wvb = (ushort_t*)(base + (16ull << 20));  // 2 MB
    ushort_t* Wob = (ushort_t*)(base + (18ull << 20));  // 2 MB
    ushort_t* qhb = (ushort_t*)(base + (20ull << 20));  // 4 MB
    ushort_t* khb = (ushort_t*)(base + (24ull << 20));  // 4 MB
    ushort_t* vhb = (ushort_t*)(base + (28ull << 20));  // 4 MB
    ushort_t* vT  = qb;   // alias: qb dead after proj_gemm
    ushort_t* aob = kb;   // alias: kb dead after proj_gemm

    float* out  = (float*)d_out;
    float* attn = out + (size_t)BB * TT * DD;

    cvt_all<<<dim3(1024, 7), 256, 0, stream>>>(q, k, v, Wq, Wk, Wv, Wo,
                                               qb, kb, vb, Wqb, Wkb, Wvb, Wob);
    proj_gemm<<<dim3(8, 16, 3), 256, 0, stream>>>(qb, kb, vb, Wqb, Wkb, Wvb,
                                                  bq, bk, bv, qhb, khb, vhb);
    transpose_v<<<dim3(16, 32), 256, 0, stream>>>(vhb, vT);
    scores_mfma<<<dim3(36, 32), 256, 0, stream>>>(qhb, khb, attn);
    sav_fused<<<dim3(16, 32), 512, 0, stream>>>(attn, attn_bias, bscale, vT,
                                                attn, aob);
    oproj_gemm<<<dim3(8, 16), 256, 0, stream>>>(aob, Wob, bo, out);
}

// Round 6
// 373.188 us; speedup vs baseline: 1.1380x; 1.1380x over previous
//
#include <hip/hip_runtime.h>
#include <hip/hip_bf16.h>
#include <math.h>

#define BB 2
#define TT 1024
#define SS 1024
#define DD 1024
#define HH 16
#define DH 64

typedef __attribute__((ext_vector_type(8))) short bf16x8;
typedef __attribute__((ext_vector_type(4))) float f32x4;
typedef unsigned short ushort_t;

#define AS3(p) ((__attribute__((address_space(3))) unsigned int*)(p))
#define AS1(p) ((const __attribute__((address_space(1))) unsigned int*)(p))

__device__ __forceinline__ unsigned short f2b(float f) {
    union { float f; unsigned u; } x; x.f = f;
    unsigned r = x.u + 0x7FFFu + ((x.u >> 16) & 1u);
    return (unsigned short)(r >> 16);
}

// pack 8 f32 -> bf16x8 via v_cvt_pk_bf16_f32 (RNE)
__device__ __forceinline__ bf16x8 pack_bf16x8(float4 a, float4 b) {
    union { unsigned u[4]; bf16x8 v; } r;
    asm("v_cvt_pk_bf16_f32 %0, %1, %2" : "=v"(r.u[0]) : "v"(a.x), "v"(a.y));
    asm("v_cvt_pk_bf16_f32 %0, %1, %2" : "=v"(r.u[1]) : "v"(a.z), "v"(a.w));
    asm("v_cvt_pk_bf16_f32 %0, %1, %2" : "=v"(r.u[2]) : "v"(b.x), "v"(b.y));
    asm("v_cvt_pk_bf16_f32 %0, %1, %2" : "=v"(r.u[3]) : "v"(b.z), "v"(b.w));
    return r.v;
}

// ---------------------------------------------------------------------------
// fp32 -> bf16 conversion: ONE kernel for all 7 tensors.
// ---------------------------------------------------------------------------
__global__ __launch_bounds__(256) void cvt_all(
    const float* __restrict__ q, const float* __restrict__ k, const float* __restrict__ v,
    const float* __restrict__ Wq, const float* __restrict__ Wk,
    const float* __restrict__ Wv, const float* __restrict__ Wo,
    ushort_t* __restrict__ oq, ushort_t* __restrict__ ok, ushort_t* __restrict__ ov,
    ushort_t* __restrict__ oWq, ushort_t* __restrict__ oWk,
    ushort_t* __restrict__ oWv, ushort_t* __restrict__ oWo)
{
    const int y = blockIdx.y;
    if (y >= 3 && blockIdx.x >= 512) return;
    const float* src =
        (y == 0) ? q : (y == 1) ? k : (y == 2) ? v :
        (y == 3) ? Wq : (y == 4) ? Wk : (y == 5) ? Wv : Wo;
    ushort_t* dst =
        (y == 0) ? oq : (y == 1) ? ok : (y == 2) ? ov :
        (y == 3) ? oWq : (y == 4) ? oWk : (y == 5) ? oWv : oWo;
    size_t i = ((size_t)blockIdx.x * 256 + threadIdx.x) * 8;
    float4 v0 = *(const float4*)&src[i];
    float4 v1 = *(const float4*)&src[i + 4];
    uint4 o;
    o.x = f2b(v0.x) | ((unsigned)f2b(v0.y) << 16);
    o.y = f2b(v0.z) | ((unsigned)f2b(v0.w) << 16);
    o.z = f2b(v1.x) | ((unsigned)f2b(v1.y) << 16);
    o.w = f2b(v1.z) | ((unsigned)f2b(v1.w) << 16);
    *(uint4*)&dst[i] = o;
}

// ---------------------------------------------------------------------------
// 128x128 bf16 MFMA GEMM mainloop: BK=32 ping-pong double buffer.
// ---------------------------------------------------------------------------
__device__ __forceinline__ void gemm128_mainloop(
    const ushort_t* __restrict__ A,
    const ushort_t* __restrict__ Bw,
    int K, ushort_t (*Asm)[128 * 32], ushort_t (*Bsm)[128 * 32],
    f32x4 acc[4][4])
{
    const int tid = threadIdx.x;
    const int wave = tid >> 6, lane = tid & 63;
    const int sr = lane >> 2;
    const int gc = (lane & 3) ^ ((lane >> 3) & 3);
    const int l15 = lane & 15, q = lane >> 4;
    const int mblk = (wave >> 1) * 64, nblk = (wave & 1) * 64;

#define G128_STAGE(k0_, b_) do {                                               \
        _Pragma("unroll")                                                      \
        for (int o = 0; o < 2; o++) {                                          \
            int r0 = (wave * 2 + o) * 16;                                      \
            __builtin_amdgcn_global_load_lds(                                  \
                AS1(A + (size_t)(r0 + sr) * K + (k0_) + gc * 8),               \
                AS3(Asm[b_] + r0 * 32), 16, 0, 0);                             \
            __builtin_amdgcn_global_load_lds(                                  \
                AS1(Bw + (size_t)(r0 + sr) * K + (k0_) + gc * 8),              \
                AS3(Bsm[b_] + r0 * 32), 16, 0, 0);                             \
        } } while (0)

#define G128_COMPUTE(b_) do {                                                  \
        bf16x8 av[4], bv[4];                                                   \
        _Pragma("unroll")                                                      \
        for (int mi = 0; mi < 4; mi++) {                                       \
            int r = mblk + mi * 16 + l15;                                      \
            av[mi] = *(const bf16x8*)&Asm[b_][r * 32 + (q ^ ((r >> 1) & 3)) * 8]; \
        }                                                                      \
        _Pragma("unroll")                                                      \
        for (int ni = 0; ni < 4; ni++) {                                       \
            int r = nblk + ni * 16 + l15;                                      \
            bv[ni] = *(const bf16x8*)&Bsm[b_][r * 32 + (q ^ ((r >> 1) & 3)) * 8]; \
        }                                                                      \
        _Pragma("unroll")                                                      \
        for (int mi = 0; mi < 4; mi++)                                         \
            _Pragma("unroll")                                                  \
            for (int ni = 0; ni < 4; ni++)                                     \
                acc[mi][ni] = __builtin_amdgcn_mfma_f32_16x16x32_bf16(         \
                    av[mi], bv[ni], acc[mi][ni], 0, 0, 0);                     \
        } while (0)

    G128_STAGE(0, 0);
    __syncthreads();

    int buf = 0;
    for (int k0 = 0; k0 < K; k0 += 32) {
        if (k0 + 32 < K) G128_STAGE(k0 + 32, buf ^ 1);
        G128_COMPUTE(buf);
        __syncthreads();
        buf ^= 1;
    }
#undef G128_STAGE
#undef G128_COMPUTE
}

// Fused Q/K/V projections.
__global__ __launch_bounds__(256) void proj_gemm(
    const ushort_t* __restrict__ qb, const ushort_t* __restrict__ kb, const ushort_t* __restrict__ vb,
    const ushort_t* __restrict__ Wqb, const ushort_t* __restrict__ Wkb, const ushort_t* __restrict__ Wvb,
    const float* __restrict__ bq, const float* __restrict__ bk, const float* __restrict__ bv,
    ushort_t* __restrict__ qh, ushort_t* __restrict__ kh, ushort_t* __restrict__ vh)
{
    __shared__ ushort_t Asm[2][128 * 32];
    __shared__ ushort_t Bsm[2][128 * 32];
    const int z = blockIdx.z;
    const ushort_t* A = (z == 0) ? qb : (z == 1) ? kb : vb;
    const ushort_t* W = (z == 0) ? Wqb : (z == 1) ? Wkb : Wvb;
    const float* bias = (z == 0) ? bq : (z == 1) ? bk : bv;
    ushort_t* Y = (z == 0) ? qh : (z == 1) ? kh : vh;

    const int bm = blockIdx.y * 128, bn = blockIdx.x * 128;
    f32x4 acc[4][4];
    #pragma unroll
    for (int i = 0; i < 4; i++)
        #pragma unroll
        for (int j = 0; j < 4; j++) acc[i][j] = (f32x4)(0.f);

    gemm128_mainloop(A + (size_t)bm * DD, W + (size_t)bn * DD, DD, Asm, Bsm, acc);

    const int lane = threadIdx.x & 63, wave = threadIdx.x >> 6;
    const int mblk = (wave >> 1) * 64, nblk = (wave & 1) * 64;
    const int l15 = lane & 15, q = lane >> 4;
    #pragma unroll
    for (int mi = 0; mi < 4; mi++) {
        #pragma unroll
        for (int ni = 0; ni < 4; ni++) {
            int col = bn + nblk + ni * 16 + l15;
            float bcol = bias[col];
            #pragma unroll
            for (int r = 0; r < 4; r++) {
                int row = bm + mblk + mi * 16 + q * 4 + r;
                Y[(size_t)row * DD + col] = f2b(acc[mi][ni][r] + bcol);
            }
        }
    }
}

// Output projection: bf16 in, fp32 out + bias.
__global__ __launch_bounds__(256) void oproj_gemm(
    const ushort_t* __restrict__ A, const ushort_t* __restrict__ W,
    const float* __restrict__ bias, float* __restrict__ Y)
{
    __shared__ ushort_t Asm[2][128 * 32];
    __shared__ ushort_t Bsm[2][128 * 32];
    const int bm = blockIdx.y * 128, bn = blockIdx.x * 128;
    f32x4 acc[4][4];
    #pragma unroll
    for (int i = 0; i < 4; i++)
        #pragma unroll
        for (int j = 0; j < 4; j++) acc[i][j] = (f32x4)(0.f);

    gemm128_mainloop(A + (size_t)bm * DD, W + (size_t)bn * DD, DD, Asm, Bsm, acc);

    const int lane = threadIdx.x & 63, wave = threadIdx.x >> 6;
    const int mblk = (wave >> 1) * 64, nblk = (wave & 1) * 64;
    const int l15 = lane & 15, q = lane >> 4;
    #pragma unroll
    for (int mi = 0; mi < 4; mi++) {
        #pragma unroll
        for (int ni = 0; ni < 4; ni++) {
            int col = bn + nblk + ni * 16 + l15;
            float bcol = bias[col];
            #pragma unroll
            for (int r = 0; r < 4; r++) {
                int row = bm + mblk + mi * 16 + q * 4 + r;
                Y[(size_t)row * DD + col] = acc[mi][ni][r] + bcol;
            }
        }
    }
}

// ---------------------------------------------------------------------------
// V transpose: vh (B,S,H,DH) bf16 -> vT (B,H,DH,S) bf16
// ---------------------------------------------------------------------------
__global__ __launch_bounds__(256) void transpose_v(
    const ushort_t* __restrict__ vh, ushort_t* __restrict__ vT)
{
    __shared__ ushort_t Ls[64][72];
    const int s0 = blockIdx.x * 64;
    const int bh = blockIdx.y;
    const int b = bh >> 4, h = bh & 15;
    const int tid = threadIdx.x;
    const int r = tid >> 2, c16 = (tid & 3) * 16;

    const ushort_t* src = &vh[((size_t)(b * SS + s0 + r) * HH + h) * DH + c16];
    uint4 u0 = *(const uint4*)src;
    uint4 u1 = *(const uint4*)(src + 8);
    ushort_t tmp[16];
    *(uint4*)&tmp[0] = u0; *(uint4*)&tmp[8] = u1;
    #pragma unroll
    for (int j = 0; j < 16; j++) Ls[c16 + j][r] = tmp[j];
    __syncthreads();

    const int dh = r;
    uint4 w0 = *(const uint4*)&Ls[dh][c16];
    uint4 w1 = *(const uint4*)&Ls[dh][c16 + 8];
    ushort_t* dst = &vT[((size_t)bh * DH + dh) * SS + s0 + c16];
    *(uint4*)dst = w0;
    *(uint4*)(dst + 8) = w1;
}

// ---------------------------------------------------------------------------
// scores + softmax-numerator (fixed reference m=16, validated R5) + tanh bias:
// w[bh,t,s] = exp(clip(qk/8)-16) * max(1+bscale*tanh(bias),1e-9), 0 if masked.
// Writes w fp32 to the attn buffer + per-row partial sums (P=sum p, W=sum w)
// to Ppart/Wpart[row*8 + si]. 128x128 causal tiles, 1152 blocks.
// ---------------------------------------------------------------------------
__global__ __launch_bounds__(256) void scores_sm_mfma(
    const ushort_t* __restrict__ qh, const ushort_t* __restrict__ kh,
    const float* __restrict__ attn_bias, const float* __restrict__ bias_scale_p,
    float* __restrict__ wout, float* __restrict__ Ppart, float* __restrict__ Wpart)
{
    __shared__ ushort_t Qs[128 * 64];
    __shared__ ushort_t Ks[128 * 64];
    __shared__ float pPs[128][2];
    __shared__ float pWs[128][2];

    int idx = blockIdx.x, ti = 0;
    while (idx >= ti + 1) { idx -= ti + 1; ti++; }
    const int si = idx;
    const int bh = blockIdx.y;
    const int b = bh >> 4, h = bh & 15;
    const int t0 = ti * 128, s0 = si * 128;

    const int tid = threadIdx.x;
    const int wave = tid >> 6, lane = tid & 63;
    const int sr8 = lane >> 3;
    const int gc8 = (lane & 7) ^ sr8;

    #pragma unroll
    for (int o = 0; o < 4; o++) {
        int r0 = (wave * 4 + o) * 8;
        int r = r0 + sr8;
        __builtin_amdgcn_global_load_lds(
            AS1(qh + ((size_t)(b * TT + t0 + r) * HH + h) * DH + gc8 * 8),
            AS3(Qs + r0 * 64), 16, 0, 0);
        __builtin_amdgcn_global_load_lds(
            AS1(kh + ((size_t)(b * SS + s0 + r) * HH + h) * DH + gc8 * 8),
            AS3(Ks + r0 * 64), 16, 0, 0);
    }
    __syncthreads();

    const int l15 = lane & 15, q = lane >> 4;
    const int tblk = (wave >> 1) * 64, sblk = (wave & 1) * 64;
    f32x4 acc[4][4];
    #pragma unroll
    for (int i = 0; i < 4; i++)
        #pragma unroll
        for (int j = 0; j < 4; j++) acc[i][j] = (f32x4)(0.f);

    #pragma unroll
    for (int ks = 0; ks < 2; ks++) {
        bf16x8 av[4], bv[4];
        #pragma unroll
        for (int mi = 0; mi < 4; mi++) {
            int r = tblk + mi * 16 + l15;
            av[mi] = *(const bf16x8*)&Qs[r * 64 + ((ks * 4 + q) ^ (r & 7)) * 8];
        }
        #pragma unroll
        for (int ni = 0; ni < 4; ni++) {
            int r = sblk + ni * 16 + l15;
            bv[ni] = *(const bf16x8*)&Ks[r * 64 + ((ks * 4 + q) ^ (r & 7)) * 8];
        }
        #pragma unroll
        for (int mi = 0; mi < 4; mi++)
            #pragma unroll
            for (int ni = 0; ni < 4; ni++)
                acc[mi][ni] = __builtin_amdgcn_mfma_f32_16x16x32_bf16(av[mi], bv[ni], acc[mi][ni], 0, 0, 0);
    }

    // per-element: clip, exp(s-16), bias scale, write w, accumulate partials
    const float bscale = bias_scale_p[0];
    float rowP[4][4], rowW[4][4];
    #pragma unroll
    for (int mi = 0; mi < 4; mi++)
        #pragma unroll
        for (int r = 0; r < 4; r++) { rowP[mi][r] = 0.f; rowW[mi][r] = 0.f; }

    #pragma unroll
    for (int mi = 0; mi < 4; mi++) {
        #pragma unroll
        for (int ni = 0; ni < 4; ni++) {
            int scol = s0 + sblk + ni * 16 + l15;
            #pragma unroll
            for (int r = 0; r < 4; r++) {
                int t = t0 + tblk + mi * 16 + q * 4 + r;
                float s = acc[mi][ni][r] * 0.125f;
                s = fminf(fmaxf(s, -80.f), 80.f);
                float p = (scol <= t) ? __expf(s - 16.f) : 0.f;
                float bvv = attn_bias[((size_t)bh * TT + t) * SS + scol];
                float e = __expf(-2.f * fabsf(bvv));
                float th = copysignf((1.f - e) / (1.f + e), bvv);
                float sc = fmaxf(1.f + bscale * th, 1e-9f);
                float w = p * sc;
                wout[((size_t)bh * TT + t) * SS + scol] = w;
                rowP[mi][r] += p;
                rowW[mi][r] += w;
            }
        }
    }

    // reduce over the 16 l15 lanes (same row group)
    #pragma unroll
    for (int off = 1; off < 16; off <<= 1) {
        #pragma unroll
        for (int mi = 0; mi < 4; mi++)
            #pragma unroll
            for (int r = 0; r < 4; r++) {
                rowP[mi][r] += __shfl_xor(rowP[mi][r], off);
                rowW[mi][r] += __shfl_xor(rowW[mi][r], off);
            }
    }
    if (l15 == 0) {
        #pragma unroll
        for (int mi = 0; mi < 4; mi++)
            #pragma unroll
            for (int r = 0; r < 4; r++) {
                int row = tblk + mi * 16 + q * 4 + r;
                pPs[row][wave & 1] = rowP[mi][r];
                pWs[row][wave & 1] = rowW[mi][r];
            }
    }
    __syncthreads();
    if (tid < 128) {
        float P2 = pPs[tid][0] + pPs[tid][1];
        float W2 = pWs[tid][0] + pWs[tid][1];
        size_t o = ((size_t)bh * TT + t0 + tid) * 8 + si;
        Ppart[o] = P2;
        Wpart[o] = W2;
    }
}

// ---------------------------------------------------------------------------
// AV + attn normalization writeout. 64t x 64dh per block, 64-wide s-steps.
// inv[t] = 1/(W+1e-9P) from partials (computed once, 64 threads).
// Per s-tile: stage V (bf16) + w-tile (fp32, 16KB, linear) via global_load_lds;
// MFMA A-fragments read direct from global (L2-hot, just staged);
// writeback attn = w * inv from Wsm with coalesced linear mapping.
// Zero (masked) tiles stored up front. Heavy blocks first. LDS 48KB.
// ---------------------------------------------------------------------------
__global__ __launch_bounds__(256) void av_norm_mfma(
    const float* __restrict__ w, const ushort_t* __restrict__ vT,
    const float* __restrict__ Ppart, const float* __restrict__ Wpart,
    float* __restrict__ attn, ushort_t* __restrict__ ao)
{
    __shared__ ushort_t Vsm[2][64 * 64];   // 16 KB
    __shared__ float Wsm[2][64 * 64];      // 32 KB
    __shared__ float sInv[64];

    const int tb = (int)gridDim.x - 1 - (int)blockIdx.x;   // heavy first
    const int bh = blockIdx.y;
    const int b = bh >> 4, h = bh & 15;
    const int t0 = tb * 64;
    const int nst = tb + 1;

    const int tid = threadIdx.x;
    const int wave = tid >> 6, lane = tid & 63;
    const int sr8 = lane >> 3, gc8 = (lane & 7) ^ sr8;
    const int l15 = lane & 15, q = lane >> 4;

    // per-row inverse normalizer
    if (tid < 64) {
        int t = t0 + tid;
        int n2 = (t >> 7) + 1;
        const float* pp = Ppart + ((size_t)bh * TT + t) * 8;
        const float* ww = Wpart + ((size_t)bh * TT + t) * 8;
        float P = 0.f, W = 0.f;
        for (int j = 0; j < n2; j++) { P += pp[j]; W += ww[j]; }
        sInv[tid] = 1.f / (W + 1e-9f * P);
    }

    float* aout_base = attn + ((size_t)bh * TT + t0) * SS;

    // zero-fill fully-masked tiles (stores drain under compute)
    {
        float4 z = make_float4(0.f, 0.f, 0.f, 0.f);
        const int zr = tid >> 4, zc = (tid & 15) * 4;
        for (int si = nst; si < SS / 64; si++)
            #pragma unroll
            for (int kk = 0; kk < 4; kk++)
                *(float4*)&aout_base[(size_t)(zr + kk * 16) * SS + si * 64 + zc] = z;
    }

    const float* arow = w + ((size_t)bh * TT + t0 + wave * 16 + l15) * SS + q * 8;
    const ushort_t* vbase = vT + (size_t)bh * DH * SS;
    const float* wtile_base = w + ((size_t)bh * TT + t0) * SS;

    f32x4 acc[4];
    #pragma unroll
    for (int i = 0; i < 4; i++) acc[i] = (f32x4)(0.f);

#define STAGE_V(sidx, bb) do {                                                \
        _Pragma("unroll")                                                     \
        for (int o = 0; o < 2; o++) {                                         \
            int r0 = wave * 16 + o * 8;                                       \
            __builtin_amdgcn_global_load_lds(                                 \
                AS1(vbase + (size_t)(r0 + sr8) * SS + (sidx) * 64 + gc8 * 8), \
                AS3(&Vsm[bb][r0 * 64]), 16, 0, 0);                            \
        } } while (0)

#define STAGE_W(sidx, bb) do {                                                \
        _Pragma("unroll")                                                     \
        for (int i_ = 0; i_ < 4; i_++) {                                      \
            int row_ = wave * 16 + i_ * 4 + (lane >> 4);                      \
            __builtin_amdgcn_global_load_lds(                                 \
                AS1(wtile_base + (size_t)row_ * SS + (sidx) * 64 + (lane & 15) * 4), \
                AS3(&Wsm[bb][wave * 1024 + i_ * 256]), 16, 0, 0);             \
        } } while (0)

#define LOAD_A(sidx, dst) do {                                                \
        const float* p_ = arow + (sidx) * 64;                                 \
        dst[0] = *(const float4*)(p_);                                        \
        dst[1] = *(const float4*)(p_ + 4);                                    \
        dst[2] = *(const float4*)(p_ + 32);                                   \
        dst[3] = *(const float4*)(p_ + 36); } while (0)

#define COMPUTE(bb, ax) do {                                                  \
        bf16x8 af0 = pack_bf16x8(ax[0], ax[1]);                               \
        bf16x8 af1 = pack_bf16x8(ax[2], ax[3]);                               \
        _Pragma("unroll")                                                     \
        for (int ni = 0; ni < 4; ni++) {                                      \
            int rv = ni * 16 + l15;                                           \
            bf16x8 b0 = *(const bf16x8*)&Vsm[bb][rv * 64 + ((q) ^ (rv & 7)) * 8];       \
            bf16x8 b1 = *(const bf16x8*)&Vsm[bb][rv * 64 + ((4 + q) ^ (rv & 7)) * 8];   \
            acc[ni] = __builtin_amdgcn_mfma_f32_16x16x32_bf16(af0, b0, acc[ni], 0, 0, 0);\
            acc[ni] = __builtin_amdgcn_mfma_f32_16x16x32_bf16(af1, b1, acc[ni], 0, 0, 0);\
        } } while (0)

#define WRITEBACK(bb, sidx) do {                                              \
        const int wc_ = (tid & 15) * 4;                                       \
        _Pragma("unroll")                                                     \
        for (int kk = 0; kk < 4; kk++) {                                      \
            int row_ = (tid >> 4) + kk * 16;                                  \
            float4 vv = *(const float4*)&Wsm[bb][row_ * 64 + wc_];            \
            float iv_ = sInv[row_];                                           \
            vv.x *= iv_; vv.y *= iv_; vv.z *= iv_; vv.w *= iv_;               \
            *(float4*)&aout_base[(size_t)row_ * SS + (sidx) * 64 + wc_] = vv; \
        } } while (0)

    float4 aA[4], aB[4];
    STAGE_V(0, 0);
    STAGE_W(0, 0);
    LOAD_A(0, aA);
    __syncthreads();   // drains stage(0); also publishes sInv

    int st = 0;
    while (true) {
        if (st + 1 < nst) { STAGE_V(st + 1, 1); STAGE_W(st + 1, 1); LOAD_A(st + 1, aB); }
        COMPUTE(0, aA);
        WRITEBACK(0, st);
        __syncthreads();
        if (++st == nst) break;
        if (st + 1 < nst) { STAGE_V(st + 1, 0); STAGE_W(st + 1, 0); LOAD_A(st + 1, aA); }
        COMPUTE(1, aB);
        WRITEBACK(1, st);
        __syncthreads();
        if (++st == nst) break;
    }
#undef STAGE_V
#undef STAGE_W
#undef LOAD_A
#undef COMPUTE
#undef WRITEBACK

    // ao output: bf16, scaled by per-row inv
    #pragma unroll
    for (int ni = 0; ni < 4; ni++) {
        int dh = ni * 16 + l15;
        #pragma unroll
        for (int r = 0; r < 4; r++) {
            int trow = wave * 16 + q * 4 + r;
            float iv = sInv[trow];
            int t = t0 + trow;
            ao[(size_t)(b * TT + t) * DD + h * DH + dh] = f2b(acc[ni][r] * iv);
        }
    }
}

// ---------------------------------------------------------------------------
extern "C" void kernel_launch(void* const* d_in, const int* in_sizes, int n_in,
                              void* d_out, int out_size, void* d_ws, size_t ws_size,
                              hipStream_t stream)
{
    const float* q   = (const float*)d_in[0];
    const float* k   = (const float*)d_in[1];
    const float* v   = (const float*)d_in[2];
    const float* attn_bias = (const float*)d_in[4];
    const float* Wq = (const float*)d_in[5];
    const float* bq = (const float*)d_in[6];
    const float* Wk = (const float*)d_in[7];
    const float* bk = (const float*)d_in[8];
    const float* Wv = (const float*)d_in[9];
    const float* bv = (const float*)d_in[10];
    const float* Wo = (const float*)d_in[11];
    const float* bo = (const float*)d_in[12];
    const float* bscale = (const float*)d_in[13];

    // ws layout (32 MB total, with aliasing):
    char* base = (char*)d_ws;
    ushort_t* qb  = (ushort_t*)(base + (0ull << 20));   // 4 MB, later vT
    ushort_t* kb  = (ushort_t*)(base + (4ull << 20));   // 4 MB, later ao
    ushort_t* vb  = (ushort_t*)(base + (8ull << 20));   // 4 MB, later P/W parts
    ushort_t* Wqb = (ushort_t*)(base + (12ull << 20));  // 2 MB
    ushort_t* Wkb = (ushort_t*)(base + (14ull << 20));  // 2 MB
    ushort_t* Wvb = (ushort_t*)(base + (16ull << 20));  // 2 MB
    ushort_t* Wob = (ushort_t*)(base + (18ull << 20));  // 2 MB
    ushort_t* qhb = (ushort_t*)(base + (20ull << 20));  // 4 MB
    ushort_t* khb = (ushort_t*)(base + (24ull << 20));  // 4 MB
    ushort_t* vhb = (ushort_t*)(base + (28ull << 20));  // 4 MB
    ushort_t* vT  = qb;                         // alias: qb dead after proj
    ushort_t* aob = kb;                         // alias: kb dead after proj
    float* PpartB = (float*)(base + (8ull << 20));      // 1 MB (vb dead)
    float* WpartB = (float*)(base + (9ull << 20));      // 1 MB

    float* out  = (float*)d_out;
    float* attn = out + (size_t)BB * TT * DD;

    cvt_all<<<dim3(1024, 7), 256, 0, stream>>>(q, k, v, Wq, Wk, Wv, Wo,
                                               qb, kb, vb, Wqb, Wkb, Wvb, Wob);
    proj_gemm<<<dim3(8, 16, 3), 256, 0, stream>>>(qb, kb, vb, Wqb, Wkb, Wvb,
                                                  bq, bk, bv, qhb, khb, vhb);
    transpose_v<<<dim3(16, 32), 256, 0, stream>>>(vhb, vT);
    scores_sm_mfma<<<dim3(36, 32), 256, 0, stream>>>(qhb, khb, attn_bias, bscale,
                                                     attn, PpartB, WpartB);
    av_norm_mfma<<<dim3(16, 32), 256, 0, stream>>>(attn, vT, PpartB, WpartB,
                                                   attn, aob);
    oproj_gemm<<<dim3(8, 16), 256, 0, stream>>>(aob, Wob, bo, out);
}

// Round 7
// 366.021 us; speedup vs baseline: 1.1603x; 1.0196x over previous
//
#include <hip/hip_runtime.h>
#include <hip/hip_bf16.h>
#include <math.h>

#define BB 2
#define TT 1024
#define SS 1024
#define DD 1024
#define HH 16
#define DH 64

typedef __attribute__((ext_vector_type(8))) short bf16x8;
typedef __attribute__((ext_vector_type(4))) float f32x4;
typedef unsigned short ushort_t;

#define AS3(p) ((__attribute__((address_space(3))) unsigned int*)(p))
#define AS1(p) ((const __attribute__((address_space(1))) unsigned int*)(p))

__device__ __forceinline__ unsigned short f2b(float f) {
    union { float f; unsigned u; } x; x.f = f;
    unsigned r = x.u + 0x7FFFu + ((x.u >> 16) & 1u);
    return (unsigned short)(r >> 16);
}

// pack 8 f32 -> bf16x8 via v_cvt_pk_bf16_f32 (RNE)
__device__ __forceinline__ bf16x8 pack_bf16x8(float4 a, float4 b) {
    union { unsigned u[4]; bf16x8 v; } r;
    asm("v_cvt_pk_bf16_f32 %0, %1, %2" : "=v"(r.u[0]) : "v"(a.x), "v"(a.y));
    asm("v_cvt_pk_bf16_f32 %0, %1, %2" : "=v"(r.u[1]) : "v"(a.z), "v"(a.w));
    asm("v_cvt_pk_bf16_f32 %0, %1, %2" : "=v"(r.u[2]) : "v"(b.x), "v"(b.y));
    asm("v_cvt_pk_bf16_f32 %0, %1, %2" : "=v"(r.u[3]) : "v"(b.z), "v"(b.w));
    return r.v;
}

// ---------------------------------------------------------------------------
// fp32 -> bf16 conversion: ONE kernel for all 7 tensors.
// ---------------------------------------------------------------------------
__global__ __launch_bounds__(256) void cvt_all(
    const float* __restrict__ q, const float* __restrict__ k, const float* __restrict__ v,
    const float* __restrict__ Wq, const float* __restrict__ Wk,
    const float* __restrict__ Wv, const float* __restrict__ Wo,
    ushort_t* __restrict__ oq, ushort_t* __restrict__ ok, ushort_t* __restrict__ ov,
    ushort_t* __restrict__ oWq, ushort_t* __restrict__ oWk,
    ushort_t* __restrict__ oWv, ushort_t* __restrict__ oWo)
{
    const int y = blockIdx.y;
    if (y >= 3 && blockIdx.x >= 512) return;
    const float* src =
        (y == 0) ? q : (y == 1) ? k : (y == 2) ? v :
        (y == 3) ? Wq : (y == 4) ? Wk : (y == 5) ? Wv : Wo;
    ushort_t* dst =
        (y == 0) ? oq : (y == 1) ? ok : (y == 2) ? ov :
        (y == 3) ? oWq : (y == 4) ? oWk : (y == 5) ? oWv : oWo;
    size_t i = ((size_t)blockIdx.x * 256 + threadIdx.x) * 8;
    float4 v0 = *(const float4*)&src[i];
    float4 v1 = *(const float4*)&src[i + 4];
    uint4 o;
    o.x = f2b(v0.x) | ((unsigned)f2b(v0.y) << 16);
    o.y = f2b(v0.z) | ((unsigned)f2b(v0.w) << 16);
    o.z = f2b(v1.x) | ((unsigned)f2b(v1.y) << 16);
    o.w = f2b(v1.z) | ((unsigned)f2b(v1.w) << 16);
    *(uint4*)&dst[i] = o;
}

// ---------------------------------------------------------------------------
// 128x128 bf16 MFMA GEMM mainloop: BK=64 PING-PONG double buffer.
// 32 MFMA per barrier pair; prefetch of k+64 overlaps the 32-MFMA compute.
// LDS 64 KB -> 2 blocks/CU (enough: proj needs 1.5, oproj 0.5 blocks/CU).
// Staging/read indexing identical to the round-3 BK=64 (correctness-proven).
// ---------------------------------------------------------------------------
__device__ __forceinline__ void gemm128_mainloop(
    const ushort_t* __restrict__ A,
    const ushort_t* __restrict__ Bw,
    int K, ushort_t (*Asm)[128 * 64], ushort_t (*Bsm)[128 * 64],
    f32x4 acc[4][4])
{
    const int tid = threadIdx.x;
    const int wave = tid >> 6, lane = tid & 63;
    const int sr8 = lane >> 3;                 // row within 8-row group
    const int gc8 = (lane & 7) ^ sr8;          // swizzled global chunk (8x16B/row)
    const int l15 = lane & 15, q = lane >> 4;
    const int mblk = (wave >> 1) * 64, nblk = (wave & 1) * 64;

#define G128_STAGE(k0_, b_) do {                                               \
        _Pragma("unroll")                                                      \
        for (int o = 0; o < 4; o++) {                                          \
            int r0 = wave * 32 + o * 8;                                        \
            __builtin_amdgcn_global_load_lds(                                  \
                AS1(A + (size_t)(r0 + sr8) * K + (k0_) + gc8 * 8),             \
                AS3(Asm[b_] + r0 * 64), 16, 0, 0);                             \
            __builtin_amdgcn_global_load_lds(                                  \
                AS1(Bw + (size_t)(r0 + sr8) * K + (k0_) + gc8 * 8),            \
                AS3(Bsm[b_] + r0 * 64), 16, 0, 0);                             \
        } } while (0)

#define G128_COMPUTE(b_) do {                                                  \
        _Pragma("unroll")                                                      \
        for (int ks = 0; ks < 2; ks++) {                                       \
            bf16x8 av[4], bv[4];                                               \
            _Pragma("unroll")                                                  \
            for (int mi = 0; mi < 4; mi++) {                                   \
                int r = mblk + mi * 16 + l15;                                  \
                av[mi] = *(const bf16x8*)&Asm[b_][r * 64 + ((ks * 4 + q) ^ (r & 7)) * 8]; \
            }                                                                  \
            _Pragma("unroll")                                                  \
            for (int ni = 0; ni < 4; ni++) {                                   \
                int r = nblk + ni * 16 + l15;                                  \
                bv[ni] = *(const bf16x8*)&Bsm[b_][r * 64 + ((ks * 4 + q) ^ (r & 7)) * 8]; \
            }                                                                  \
            _Pragma("unroll")                                                  \
            for (int mi = 0; mi < 4; mi++)                                     \
                _Pragma("unroll")                                              \
                for (int ni = 0; ni < 4; ni++)                                 \
                    acc[mi][ni] = __builtin_amdgcn_mfma_f32_16x16x32_bf16(     \
                        av[mi], bv[ni], acc[mi][ni], 0, 0, 0);                 \
        } } while (0)

    G128_STAGE(0, 0);
    __syncthreads();                 // drain stage(0)

    int buf = 0;
    for (int k0 = 0; k0 < K; k0 += 64) {
        if (k0 + 64 < K) G128_STAGE(k0 + 64, buf ^ 1);   // prefetch next
        G128_COMPUTE(buf);                                // 32 MFMA
        __syncthreads();   // drains prefetch (issued a full compute ago) +
                           // protects buf reuse
        buf ^= 1;
    }
#undef G128_STAGE
#undef G128_COMPUTE
}

// Fused Q/K/V projections: z picks which. z<2 -> bf16 (B,T,D); z==2 writes
// the V projection DIRECTLY in transposed vT layout (B,H,DH,S) — 4 consecutive
// s-rows (r=0..3) pack into one 8B store. transpose_v kernel eliminated.
__global__ __launch_bounds__(256) void proj_gemm(
    const ushort_t* __restrict__ qb, const ushort_t* __restrict__ kb, const ushort_t* __restrict__ vb,
    const ushort_t* __restrict__ Wqb, const ushort_t* __restrict__ Wkb, const ushort_t* __restrict__ Wvb,
    const float* __restrict__ bq, const float* __restrict__ bk, const float* __restrict__ bv,
    ushort_t* __restrict__ qh, ushort_t* __restrict__ kh, ushort_t* __restrict__ vT)
{
    __shared__ ushort_t Asm[2][128 * 64];
    __shared__ ushort_t Bsm[2][128 * 64];
    const int z = blockIdx.z;
    const ushort_t* A = (z == 0) ? qb : (z == 1) ? kb : vb;
    const ushort_t* W = (z == 0) ? Wqb : (z == 1) ? Wkb : Wvb;
    const float* bias = (z == 0) ? bq : (z == 1) ? bk : bv;

    const int bm = blockIdx.y * 128, bn = blockIdx.x * 128;
    f32x4 acc[4][4];
    #pragma unroll
    for (int i = 0; i < 4; i++)
        #pragma unroll
        for (int j = 0; j < 4; j++) acc[i][j] = (f32x4)(0.f);

    gemm128_mainloop(A + (size_t)bm * DD, W + (size_t)bn * DD, DD, Asm, Bsm, acc);

    const int lane = threadIdx.x & 63, wave = threadIdx.x >> 6;
    const int mblk = (wave >> 1) * 64, nblk = (wave & 1) * 64;
    const int l15 = lane & 15, q = lane >> 4;

    if (z < 2) {
        ushort_t* Y = (z == 0) ? qh : kh;
        #pragma unroll
        for (int mi = 0; mi < 4; mi++) {
            #pragma unroll
            for (int ni = 0; ni < 4; ni++) {
                int col = bn + nblk + ni * 16 + l15;
                float bcol = bias[col];
                #pragma unroll
                for (int r = 0; r < 4; r++) {
                    int row = bm + mblk + mi * 16 + q * 4 + r;
                    Y[(size_t)row * DD + col] = f2b(acc[mi][ni][r] + bcol);
                }
            }
        }
    } else {
        // vT[( (b*16+h)*64 + dh ) * SS + s], s = row & 1023, b = row >> 10
        #pragma unroll
        for (int mi = 0; mi < 4; mi++) {
            int row0 = bm + mblk + mi * 16 + q * 4;
            int b_ = row0 >> 10, s0_ = row0 & 1023;
            #pragma unroll
            for (int ni = 0; ni < 4; ni++) {
                int col = bn + nblk + ni * 16 + l15;
                float bcol = bias[col];
                int h_ = col >> 6, dh_ = col & 63;
                union { unsigned u[2]; } pk;
                pk.u[0] = (unsigned)f2b(acc[mi][ni][0] + bcol)
                        | ((unsigned)f2b(acc[mi][ni][1] + bcol) << 16);
                pk.u[1] = (unsigned)f2b(acc[mi][ni][2] + bcol)
                        | ((unsigned)f2b(acc[mi][ni][3] + bcol) << 16);
                *(uint2*)&vT[((size_t)(b_ * 16 + h_) * 64 + dh_) * SS + s0_] =
                    make_uint2(pk.u[0], pk.u[1]);
            }
        }
    }
}

// Output projection: bf16 in, fp32 out + bias.
__global__ __launch_bounds__(256) void oproj_gemm(
    const ushort_t* __restrict__ A, const ushort_t* __restrict__ W,
    const float* __restrict__ bias, float* __restrict__ Y)
{
    __shared__ ushort_t Asm[2][128 * 64];
    __shared__ ushort_t Bsm[2][128 * 64];
    const int bm = blockIdx.y * 128, bn = blockIdx.x * 128;
    f32x4 acc[4][4];
    #pragma unroll
    for (int i = 0; i < 4; i++)
        #pragma unroll
        for (int j = 0; j < 4; j++) acc[i][j] = (f32x4)(0.f);

    gemm128_mainloop(A + (size_t)bm * DD, W + (size_t)bn * DD, DD, Asm, Bsm, acc);

    const int lane = threadIdx.x & 63, wave = threadIdx.x >> 6;
    const int mblk = (wave >> 1) * 64, nblk = (wave & 1) * 64;
    const int l15 = lane & 15, q = lane >> 4;
    #pragma unroll
    for (int mi = 0; mi < 4; mi++) {
        #pragma unroll
        for (int ni = 0; ni < 4; ni++) {
            int col = bn + nblk + ni * 16 + l15;
            float bcol = bias[col];
            #pragma unroll
            for (int r = 0; r < 4; r++) {
                int row = bm + mblk + mi * 16 + q * 4 + r;
                Y[(size_t)row * DD + col] = acc[mi][ni][r] + bcol;
            }
        }
    }
}

// ---------------------------------------------------------------------------
// scores: attn_raw[bh,t,s] = clip(qh.kh/8). 128x128 tile per block, causal
// tiles only. K=64 (one-shot staging, 2 MFMA k-steps).
// ---------------------------------------------------------------------------
__global__ __launch_bounds__(256) void scores_mfma(
    const ushort_t* __restrict__ qh, const ushort_t* __restrict__ kh,
    float* __restrict__ attn)
{
    __shared__ ushort_t Qs[128 * 64];
    __shared__ ushort_t Ks[128 * 64];

    int idx = blockIdx.x, ti = 0;
    while (idx >= ti + 1) { idx -= ti + 1; ti++; }
    const int si = idx;
    const int bh = blockIdx.y;
    const int b = bh >> 4, h = bh & 15;
    const int t0 = ti * 128, s0 = si * 128;

    const int tid = threadIdx.x;
    const int wave = tid >> 6, lane = tid & 63;
    const int sr8 = lane >> 3;
    const int gc8 = (lane & 7) ^ sr8;

    #pragma unroll
    for (int o = 0; o < 4; o++) {
        int r0 = (wave * 4 + o) * 8;
        int r = r0 + sr8;
        __builtin_amdgcn_global_load_lds(
            AS1(qh + ((size_t)(b * TT + t0 + r) * HH + h) * DH + gc8 * 8),
            AS3(Qs + r0 * 64), 16, 0, 0);
        __builtin_amdgcn_global_load_lds(
            AS1(kh + ((size_t)(b * SS + s0 + r) * HH + h) * DH + gc8 * 8),
            AS3(Ks + r0 * 64), 16, 0, 0);
    }
    __syncthreads();

    const int l15 = lane & 15, q = lane >> 4;
    const int tblk = (wave >> 1) * 64, sblk = (wave & 1) * 64;
    f32x4 acc[4][4];
    #pragma unroll
    for (int i = 0; i < 4; i++)
        #pragma unroll
        for (int j = 0; j < 4; j++) acc[i][j] = (f32x4)(0.f);

    #pragma unroll
    for (int ks = 0; ks < 2; ks++) {
        bf16x8 av[4], bv[4];
        #pragma unroll
        for (int mi = 0; mi < 4; mi++) {
            int r = tblk + mi * 16 + l15;
            av[mi] = *(const bf16x8*)&Qs[r * 64 + ((ks * 4 + q) ^ (r & 7)) * 8];
        }
        #pragma unroll
        for (int ni = 0; ni < 4; ni++) {
            int r = sblk + ni * 16 + l15;
            bv[ni] = *(const bf16x8*)&Ks[r * 64 + ((ks * 4 + q) ^ (r & 7)) * 8];
        }
        #pragma unroll
        for (int mi = 0; mi < 4; mi++)
            #pragma unroll
            for (int ni = 0; ni < 4; ni++)
                acc[mi][ni] = __builtin_amdgcn_mfma_f32_16x16x32_bf16(av[mi], bv[ni], acc[mi][ni], 0, 0, 0);
    }

    #pragma unroll
    for (int mi = 0; mi < 4; mi++) {
        #pragma unroll
        for (int ni = 0; ni < 4; ni++) {
            int scol = s0 + sblk + ni * 16 + l15;
            #pragma unroll
            for (int r = 0; r < 4; r++) {
                int t = t0 + tblk + mi * 16 + q * 4 + r;
                float v = acc[mi][ni][r] * 0.125f;
                v = fminf(fmaxf(v, -80.f), 80.f);
                attn[((size_t)bh * TT + t) * SS + scol] = v;
            }
        }
    }
}

// ---------------------------------------------------------------------------
// softmax + multiplicative tanh bias + renormalize: ONE WAVE PER ROW.
// Fixed reference m=16 (validated R5/R6): no row-max pass at all.
// Row in registers, all reductions via __shfl_xor, no barriers / LDS.
// ---------------------------------------------------------------------------
__global__ __launch_bounds__(256) void softmax_bias_wave(
    const float* __restrict__ attn_bias, const float* __restrict__ bias_scale_p,
    float* __restrict__ attn)
{
    const int wave = threadIdx.x >> 6, lane = threadIdx.x & 63;
    const int row = blockIdx.x * 4 + wave;          // (bh*TT + t), 0..32767
    const int t = row & (TT - 1);

    float* prow = attn + (size_t)row * SS;
    const float* brow = attn_bias + (size_t)row * SS;
    const float bscale = bias_scale_p[0];

    const int nc = (t >> 8) + 1;   // # of 256-wide chunks containing s <= t

    float w[16];
    float P = 0.f, Wn = 0.f;
    #pragma unroll
    for (int c = 0; c < 4; c++) {
        const int s0 = c * 256 + lane * 4;
        if (c < nc) {                      // wave-uniform branch
            float4 rv = *(const float4*)&prow[s0];
            float4 bv = *(const float4*)&brow[s0];
            float sv[4] = {rv.x, rv.y, rv.z, rv.w};
            float bx[4] = {bv.x, bv.y, bv.z, bv.w};
            #pragma unroll
            for (int j = 0; j < 4; j++) {
                float p = (s0 + j <= t) ? __expf(sv[j] - 16.f) : 0.f;
                float e = __expf(-2.f * fabsf(bx[j]));
                float th = copysignf((1.f - e) / (1.f + e), bx[j]);
                float sc = fmaxf(1.f + bscale * th, 1e-9f);
                float ww = p * sc;
                w[c * 4 + j] = ww;
                P += p; Wn += ww;
            }
        } else {
            w[c * 4 + 0] = 0.f; w[c * 4 + 1] = 0.f;
            w[c * 4 + 2] = 0.f; w[c * 4 + 3] = 0.f;
        }
    }
    #pragma unroll
    for (int off = 1; off < 64; off <<= 1) {
        P  += __shfl_xor(P, off);
        Wn += __shfl_xor(Wn, off);
    }
    // final = p*sc / (Σp*sc + 1e-9*Σp)
    const float inv = 1.f / (Wn + 1e-9f * P);

    #pragma unroll
    for (int c = 0; c < 4; c++) {
        const int s0 = c * 256 + lane * 4;
        float4 o;
        o.x = w[c * 4 + 0] * inv; o.y = w[c * 4 + 1] * inv;
        o.z = w[c * 4 + 2] * inv; o.w = w[c * 4 + 3] * inv;
        *(float4*)&prow[s0] = o;
    }
}

// ---------------------------------------------------------------------------
// AV: ao[b,t,h*64+dh] = sum_s attn[bh,t,s] * V[s,dh].  64t x 64dh per block.
// 64-wide s-steps; A direct-from-global (fp32->bf16 cvt_pk); V double-buffered
// via global_load_lds (stage(t+1) -> compute(t) -> one barrier).
// ---------------------------------------------------------------------------
__global__ __launch_bounds__(256) void av_mfma(
    const float* __restrict__ attn, const ushort_t* __restrict__ vT,
    ushort_t* __restrict__ ao)
{
    __shared__ ushort_t Vsm[2][64 * 64];   // 2 x 8 KB, XOR-chunk swizzled

    const int tb = (int)gridDim.x - 1 - (int)blockIdx.x;   // heavy blocks first
    const int bh = blockIdx.y;
    const int b = bh >> 4, h = bh & 15;
    const int t0 = tb * 64;
    const int nsteps = tb + 1;

    const int tid = threadIdx.x;
    const int wave = tid >> 6, lane = tid & 63;
    const int sr8 = lane >> 3, gc8 = (lane & 7) ^ sr8;
    const int l15 = lane & 15, q = lane >> 4;

    const float* arow = attn + ((size_t)bh * TT + t0 + wave * 16 + l15) * SS + q * 8;
    const ushort_t* vbase = vT + (size_t)bh * DH * SS;

    f32x4 acc[4];
    #pragma unroll
    for (int i = 0; i < 4; i++) acc[i] = (f32x4)(0.f);

#define STAGE_V(sidx, buf) do {                                               \
        int s0_ = (sidx) * 64;                                                \
        _Pragma("unroll")                                                     \
        for (int o = 0; o < 2; o++) {                                         \
            int r0 = wave * 16 + o * 8;                                       \
            __builtin_amdgcn_global_load_lds(                                 \
                AS1(vbase + (size_t)(r0 + sr8) * SS + s0_ + gc8 * 8),         \
                AS3(&Vsm[buf][r0 * 64]), 16, 0, 0);                           \
        } } while (0)

#define LOAD_A(sidx, dst) do {                                                \
        const float* p_ = arow + (sidx) * 64;                                 \
        dst[0] = *(const float4*)(p_);                                        \
        dst[1] = *(const float4*)(p_ + 4);                                    \
        dst[2] = *(const float4*)(p_ + 32);                                   \
        dst[3] = *(const float4*)(p_ + 36); } while (0)

#define COMPUTE(buf, ax) do {                                                 \
        bf16x8 af0 = pack_bf16x8(ax[0], ax[1]);                               \
        bf16x8 af1 = pack_bf16x8(ax[2], ax[3]);                               \
        _Pragma("unroll")                                                     \
        for (int ni = 0; ni < 4; ni++) {                                      \
            int rv = ni * 16 + l15;                                           \
            bf16x8 b0 = *(const bf16x8*)&Vsm[buf][rv * 64 + ((q) ^ (rv & 7)) * 8];       \
            bf16x8 b1 = *(const bf16x8*)&Vsm[buf][rv * 64 + ((4 + q) ^ (rv & 7)) * 8];   \
            acc[ni] = __builtin_amdgcn_mfma_f32_16x16x32_bf16(af0, b0, acc[ni], 0, 0, 0);\
            acc[ni] = __builtin_amdgcn_mfma_f32_16x16x32_bf16(af1, b1, acc[ni], 0, 0, 0);\
        } } while (0)

    float4 aA[4], aB[4];
    STAGE_V(0, 0);
    LOAD_A(0, aA);
    __syncthreads();

    int st = 0;
    while (true) {
        if (st + 1 < nsteps) { STAGE_V(st + 1, 1); LOAD_A(st + 1, aB); }
        COMPUTE(0, aA);
        __syncthreads();
        if (++st == nsteps) break;
        if (st + 1 < nsteps) { STAGE_V(st + 1, 0); LOAD_A(st + 1, aA); }
        COMPUTE(1, aB);
        __syncthreads();
        if (++st == nsteps) break;
    }

#undef STAGE_V
#undef LOAD_A
#undef COMPUTE

    #pragma unroll
    for (int ni = 0; ni < 4; ni++) {
        int dh = ni * 16 + l15;
        #pragma unroll
        for (int r = 0; r < 4; r++) {
            int t = t0 + wave * 16 + q * 4 + r;
            ao[(size_t)(b * TT + t) * DD + h * DH + dh] = f2b(acc[ni][r]);
        }
    }
}

// ---------------------------------------------------------------------------
extern "C" void kernel_launch(void* const* d_in, const int* in_sizes, int n_in,
                              void* d_out, int out_size, void* d_ws, size_t ws_size,
                              hipStream_t stream)
{
    const float* q   = (const float*)d_in[0];
    const float* k   = (const float*)d_in[1];
    const float* v   = (const float*)d_in[2];
    const float* attn_bias = (const float*)d_in[4];
    const float* Wq = (const float*)d_in[5];
    const float* bq = (const float*)d_in[6];
    const float* Wk = (const float*)d_in[7];
    const float* bk = (const float*)d_in[8];
    const float* Wv = (const float*)d_in[9];
    const float* bv = (const float*)d_in[10];
    const float* Wo = (const float*)d_in[11];
    const float* bo = (const float*)d_in[12];
    const float* bscale = (const float*)d_in[13];

    // ws layout (32 MB total):
    char* base = (char*)d_ws;
    ushort_t* qb  = (ushort_t*)(base + (0ull << 20));   // 4 MB
    ushort_t* kb  = (ushort_t*)(base + (4ull << 20));   // 4 MB, later ao
    ushort_t* vb  = (ushort_t*)(base + (8ull << 20));   // 4 MB
    ushort_t* Wqb = (ushort_t*)(base + (12ull << 20));  // 2 MB
    ushort_t* Wkb = (ushort_t*)(base + (14ull << 20));  // 2 MB
    ushort_t* Wvb = (ushort_t*)(base + (16ull << 20));  // 2 MB
    ushort_t* Wob = (ushort_t*)(base + (18ull << 20));  // 2 MB
    ushort_t* qhb = (ushort_t*)(base + (20ull << 20));  // 4 MB
    ushort_t* khb = (ushort_t*)(base + (24ull << 20));  // 4 MB
    ushort_t* vT  = (ushort_t*)(base + (28ull << 20));  // 4 MB (written by proj z==2)
    ushort_t* aob = kb;   // alias: kb dead after proj_gemm

    float* out  = (float*)d_out;
    float* attn = out + (size_t)BB * TT * DD;

    cvt_all<<<dim3(1024, 7), 256, 0, stream>>>(q, k, v, Wq, Wk, Wv, Wo,
                                               qb, kb, vb, Wqb, Wkb, Wvb, Wob);
    proj_gemm<<<dim3(8, 16, 3), 256, 0, stream>>>(qb, kb, vb, Wqb, Wkb, Wvb,
                                                  bq, bk, bv, qhb, khb, vT);
    scores_mfma<<<dim3(36, 32), 256, 0, stream>>>(qhb, khb, attn);
    softmax_bias_wave<<<dim3(8192), 256, 0, stream>>>(attn_bias, bscale, attn);
    av_mfma<<<dim3(16, 32), 256, 0, stream>>>(attn, vT, aob);
    oproj_gemm<<<dim3(8, 16), 256, 0, stream>>>(aob, Wob, bo, out);
}